// Round 6
// baseline (285.356 us; speedup 1.0000x reference)
//
#include <hip/hip_runtime.h>

#define D 64
#define NK 1024
#define QTOTAL 65536
#define NELEM (QTOTAL * D)      // 4194304
#define LOSS_OFF 4194304
#define IDX_OFF  4194305

typedef float f32x16 __attribute__((ext_vector_type(16)));

// One query's 16 consecutive code elements (SGPR-resident, wave-uniform):
// 4 independent FMA chains (dim ≡ j mod 4 -> chain j), same order as R3.
#define DO_CHUNK_Q(B, K, X, c0, c1, c2, c3) \
    c0 = fmaf(B[0],  X[4*K+0].x, c0); c1 = fmaf(B[1],  X[4*K+0].y, c1); \
    c2 = fmaf(B[2],  X[4*K+0].z, c2); c3 = fmaf(B[3],  X[4*K+0].w, c3); \
    c0 = fmaf(B[4],  X[4*K+1].x, c0); c1 = fmaf(B[5],  X[4*K+1].y, c1); \
    c2 = fmaf(B[6],  X[4*K+1].z, c2); c3 = fmaf(B[7],  X[4*K+1].w, c3); \
    c0 = fmaf(B[8],  X[4*K+2].x, c0); c1 = fmaf(B[9],  X[4*K+2].y, c1); \
    c2 = fmaf(B[10], X[4*K+2].z, c2); c3 = fmaf(B[11], X[4*K+2].w, c3); \
    c0 = fmaf(B[12], X[4*K+3].x, c0); c1 = fmaf(B[13], X[4*K+3].y, c1); \
    c2 = fmaf(B[14], X[4*K+3].z, c2); c3 = fmaf(B[15], X[4*K+3].w, c3);

#define DO_CHUNK4(B, K) \
    DO_CHUNK_Q(B, K, xA, aA0, aA1, aA2, aA3) \
    DO_CHUNK_Q(B, K, xB, aB0, aB1, aB2, aB3) \
    DO_CHUNK_Q(B, K, xC, aC0, aC1, aC2, aC3) \
    DO_CHUNK_Q(B, K, xD, aD0, aD1, aD2, aD3)

// 256 blocks x 512 threads: exactly 1 block/CU (2 waves/SIMD). Block owns 256
// queries (4/lane, banked in AGPRs by the compiler); each of the 8 waves scans
// a wave-uniform 128-code slice of the codebook through SGPRs
// (s_load_dwordx16, self-contained asm: loads+waitcnt in one block, no
// in-flight SGPRs cross an asm boundary). q_lane=4 halves SMEM traffic vs R3
// (under the measured 2.33 B/cyc/CU K$ cap) and doubles per-iter VALU so
// 2 waves/SIMD fully hide SMEM latency: 2C=1164 > C+L~1030 -> VALU-bound.
__global__ __launch_bounds__(512, 2) void vq_main_kernel(const float* __restrict__ x,
                                                         const float* __restrict__ emb,
                                                         float* __restrict__ out,
                                                         float* __restrict__ ws) {
    __shared__ float e2l[NK];        // 4 KB, broadcast-read (wave-uniform addr)
    __shared__ float sm_s[2048];     // 8 KB: 8 waves x 256 local queries
    __shared__ int   sm_c[2048];     // 8 KB

    const int tid = threadIdx.x;
    const int l   = tid & 63;
    const int w   = tid >> 6;        // 0..7
    const int qbase = blockIdx.x * 256;

    // Per-block |e|^2 for all 1024 codes (2 rows/thread, deterministic).
#pragma unroll
    for (int c = 0; c < 2; ++c) {
        int row = c * 512 + tid;
        const float4* e4 = (const float4*)(emb + (long)row * D);
        float s = 0.f;
#pragma unroll
        for (int i = 0; i < D / 4; ++i) {
            float4 v = e4[i];
            s += v.x * v.x + v.y * v.y + v.z * v.z + v.w * v.w;
        }
        e2l[row] = s;
    }

    // Four queries resident per lane (256 floats -> AGPR bank).
    float4 xA[16], xB[16], xC[16], xD[16];
    {
        const float4* pA = (const float4*)(x + (long)(qbase + l) * D);
        const float4* pB = (const float4*)(x + (long)(qbase + 64 + l) * D);
        const float4* pC = (const float4*)(x + (long)(qbase + 128 + l) * D);
        const float4* pD = (const float4*)(x + (long)(qbase + 192 + l) * D);
#pragma unroll
        for (int i = 0; i < 16; ++i) { xA[i] = pA[i]; xB[i] = pB[i]; xC[i] = pC[i]; xD[i] = pD[i]; }
    }
    __syncthreads();

    const int code0 = __builtin_amdgcn_readfirstlane(w << 7);  // wave's first code
    const float* ep0 = emb + (long)code0 * D;

    float bestA = 3.4e38f, bestB = 3.4e38f, bestC = 3.4e38f, bestD = 3.4e38f;
    int idxA = 0, idxB = 0, idxC = 0, idxD = 0;

#pragma unroll 1
    for (int g = 0; g < 128; ++g) {
        const float* ep = ep0 + g * D;   // wave-uniform -> SGPR pair
        f32x16 b0, b1, b2, b3;
        asm volatile(
            "s_load_dwordx16 %0, %4, 0x0\n\t"
            "s_load_dwordx16 %1, %4, 0x40\n\t"
            "s_load_dwordx16 %2, %4, 0x80\n\t"
            "s_load_dwordx16 %3, %4, 0xC0\n\t"
            "s_waitcnt lgkmcnt(0)"
            : "=s"(b0), "=s"(b1), "=s"(b2), "=s"(b3)
            : "s"(ep));

        float aA0 = 0.f, aA1 = 0.f, aA2 = 0.f, aA3 = 0.f;
        float aB0 = 0.f, aB1 = 0.f, aB2 = 0.f, aB3 = 0.f;
        float aC0 = 0.f, aC1 = 0.f, aC2 = 0.f, aC3 = 0.f;
        float aD0 = 0.f, aD1 = 0.f, aD2 = 0.f, aD3 = 0.f;
        DO_CHUNK4(b0, 0)
        DO_CHUNK4(b1, 1)
        DO_CHUNK4(b2, 2)
        DO_CHUNK4(b3, 3)

        float e2c = e2l[code0 + g];      // uniform ds_read_b32: broadcast
        float h = 0.5f * e2c;
        int code = code0 + g;
        float sA = h - ((aA0 + aA1) + (aA2 + aA3));
        float sB = h - ((aB0 + aB1) + (aB2 + aB3));
        float sC = h - ((aC0 + aC1) + (aC2 + aC3));
        float sD = h - ((aD0 + aD1) + (aD2 + aD3));
        bool lt;
        lt = sA < bestA; bestA = lt ? sA : bestA; idxA = lt ? code : idxA;
        lt = sB < bestB; bestB = lt ? sB : bestB; idxB = lt ? code : idxB;
        lt = sC < bestC; bestC = lt ? sC : bestC; idxC = lt ? code : idxC;
        lt = sD < bestD; bestD = lt ? sD : bestD; idxD = lt ? code : idxD;
    }

    // Cross-wave merge: ascending wave == ascending code range, strict < keeps
    // the first minimum (numpy argmin tie-break preserved).
    sm_s[w * 256 + l]       = bestA;  sm_c[w * 256 + l]       = idxA;
    sm_s[w * 256 + 64 + l]  = bestB;  sm_c[w * 256 + 64 + l]  = idxB;
    sm_s[w * 256 + 128 + l] = bestC;  sm_c[w * 256 + 128 + l] = idxC;
    sm_s[w * 256 + 192 + l] = bestD;  sm_c[w * 256 + 192 + l] = idxD;
    __syncthreads();

    if (tid < 256) {
        float bs = sm_s[tid];
        int   bc = sm_c[tid];
#pragma unroll
        for (int wv = 1; wv < 8; ++wv) {
            float s = sm_s[wv * 256 + tid];
            int   c = sm_c[wv * 256 + tid];
            if (s < bs) { bs = s; bc = c; }
        }
        const int q = qbase + tid;
        out[IDX_OFF + q] = (float)bc;

        const float4* eb = (const float4*)(emb + (long)bc * D);
        const float4* xq = (const float4*)(x + (long)q * D);
        float4* oq = (float4*)(out + (long)q * D);
        float lsum = 0.f;
#pragma unroll
        for (int i = 0; i < 16; ++i) {
            float4 e = eb[i];
            float4 xx = xq[i];
            oq[i] = e;
            float dx = e.x - xx.x, dy = e.y - xx.y, dz = e.z - xx.z, dw = e.w - xx.w;
            lsum += dx * dx + dy * dy + dz * dz + dw * dw;
        }
        // tid<256 spans waves 0..3, all fully active -> 64-lane reduce each
#pragma unroll
        for (int o = 32; o > 0; o >>= 1)
            lsum += __shfl_down(lsum, o, 64);
        if ((tid & 63) == 0)
            ws[blockIdx.x * 4 + (tid >> 6)] = lsum;   // raw partial
    }
}

// Tail: reduce 1024 per-block partials -> loss. One wave.
__global__ __launch_bounds__(64) void vq_loss_kernel(const float* __restrict__ ws,
                                                     float* __restrict__ out) {
    const int l = threadIdx.x;
    float s = 0.f;
#pragma unroll
    for (int i = 0; i < 16; ++i) s += ws[l + 64 * i];
#pragma unroll
    for (int o = 32; o > 0; o >>= 1) s += __shfl_down(s, o, 64);
    if (l == 0) out[LOSS_OFF] = s * (0.25f / (float)NELEM);
}

extern "C" void kernel_launch(void* const* d_in, const int* in_sizes, int n_in,
                              void* d_out, int out_size, void* d_ws, size_t ws_size,
                              hipStream_t stream) {
    const float* inputs = (const float*)d_in[0];      // [65536, 64]
    const float* emb    = (const float*)d_in[1];      // [1024, 64]
    float* out = (float*)d_out;
    float* ws  = (float*)d_ws;                        // 1024 partial-loss floats

    vq_main_kernel<<<QTOTAL / 256, 512, 0, stream>>>(inputs, emb, out, ws);
    vq_loss_kernel<<<1, 64, 0, stream>>>(ws, out);
}

// Round 7
// 280.780 us; speedup vs baseline: 1.0163x; 1.0163x over previous
//
#include <hip/hip_runtime.h>

#define D 64
#define NK 1024
#define QTOTAL 65536
#define NELEM (QTOTAL * D)
#define LOSS_OFF 4194304
#define IDX_OUT_OFF 4194305
#define CAPQ 4096
#define MARGIN 2.0e-3f

typedef float f32x16 __attribute__((ext_vector_type(16)));
typedef short bf16x8 __attribute__((ext_vector_type(8)));
typedef float f32x4 __attribute__((ext_vector_type(4)));
typedef unsigned long long u64;
typedef unsigned int u32;
typedef unsigned short ushort_t;

// ---- ws layout (bytes) ----
#define WS_E2   0          // 1024 f32
#define WS_EH   4096       // 65536 bf16
#define WS_EM   135168     // 65536 bf16
#define WS_IDX  266240     // 65536 i32
#define WS_CNT  528384     // u32
#define WS_LIST 528640     // 4096 i32
#define WS_PF   545024     // 4096*16 f32
#define WS_PI   807168     // 4096*16 i32
#define WS_LP   1069312    // 4096 f32
#define WS_NEED 1085696

__device__ __forceinline__ ushort_t f2bf(float f) {
    u32 u = __float_as_uint(f);
    return (ushort_t)((u + 0x7FFFu + ((u >> 16) & 1u)) >> 16);
}
__device__ __forceinline__ float bf2f(ushort_t h) {
    return __uint_as_float(((u32)h) << 16);
}
__device__ __forceinline__ u64 u64min(u64 a, u64 b) { return a < b ? a : b; }
__device__ __forceinline__ u64 u64max(u64 a, u64 b) { return a > b ? a : b; }

// ---------------- K0: split x,emb into bf16 hi/mid; e2; zero counter --------
__global__ __launch_bounds__(256) void vqk0(const float* __restrict__ x,
                                            const float* __restrict__ emb,
                                            u32* __restrict__ xh32, u32* __restrict__ xm32,
                                            u32* __restrict__ eh32, u32* __restrict__ em32,
                                            float* __restrict__ e2, u32* __restrict__ cnt) {
    int gid = blockIdx.x * 256 + threadIdx.x;   // 2048 blocks -> 524288 threads
    const float2* x2 = (const float2*)x;
#pragma unroll
    for (int rep = 0; rep < 4; ++rep) {
        int i = gid + rep * 524288;             // 2097152 packed slots
        float2 v = x2[i];
        ushort_t h0 = f2bf(v.x), h1 = f2bf(v.y);
        ushort_t m0 = f2bf(v.x - bf2f(h0)), m1 = f2bf(v.y - bf2f(h1));
        xh32[i] = (u32)h0 | ((u32)h1 << 16);
        xm32[i] = (u32)m0 | ((u32)m1 << 16);
    }
    if (gid < 32768) {                          // emb: 32768 packed slots
        float2 v = ((const float2*)emb)[gid];
        ushort_t h0 = f2bf(v.x), h1 = f2bf(v.y);
        ushort_t m0 = f2bf(v.x - bf2f(h0)), m1 = f2bf(v.y - bf2f(h1));
        eh32[gid] = (u32)h0 | ((u32)h1 << 16);
        em32[gid] = (u32)m0 | ((u32)m1 << 16);
    }
    if (gid < NK) {                             // exact f32 |e|^2 (same order as R3)
        const float4* e4 = (const float4*)(emb + (long)gid * D);
        float s = 0.f;
#pragma unroll
        for (int i = 0; i < D / 4; ++i) {
            float4 v = e4[i];
            s += v.x * v.x + v.y * v.y + v.z * v.z + v.w * v.w;
        }
        e2[gid] = s;
    }
    if (gid == 0) *cnt = 0;
}

// ---------------- K1: bf16x2 MFMA coarse top-2 + margin flag ----------------
// 512 blocks x 256 thr (4 waves). Wave owns 32 queries (2 sub-tiles of 16),
// scans all 64 code-tiles. dot = hh+hm+mh (error ~6e-5 << MARGIN).
// Fragment layout (m89/m92-verified): A row m=lane&15, k=(lane>>4)*8+j;
// B row n=lane&15, same k. C/D: col=lane&15 (code), row=(lane>>4)*4+reg (query).
__global__ __launch_bounds__(256) void vqk1(const ushort_t* __restrict__ xh,
                                            const ushort_t* __restrict__ xm,
                                            const ushort_t* __restrict__ eh,
                                            const ushort_t* __restrict__ em,
                                            const float* __restrict__ e2g,
                                            int* __restrict__ idxarr,
                                            int* __restrict__ list,
                                            u32* __restrict__ cnt) {
    __shared__ float e2l[NK];
    const int tid = threadIdx.x;
    const int l = tid & 63;
    const int w = tid >> 6;
    for (int i = tid; i < NK; i += 256) e2l[i] = e2g[i];
    __syncthreads();

    const int row = l & 15;
    const int koff = (l >> 4) * 8;
    const int qbase = blockIdx.x * 128 + w * 32;

    bf16x8 ah[2][2], am[2][2];
#pragma unroll
    for (int s = 0; s < 2; ++s) {
        long b = (long)(qbase + s * 16 + row) * D + koff;
        ah[s][0] = *(const bf16x8*)(xh + b);
        ah[s][1] = *(const bf16x8*)(xh + b + 32);
        am[s][0] = *(const bf16x8*)(xm + b);
        am[s][1] = *(const bf16x8*)(xm + b + 32);
    }

    u64 t1[8], t2[8];
#pragma unroll
    for (int i = 0; i < 8; ++i) { t1[i] = ~0ULL; t2[i] = ~0ULL; }

#pragma unroll 1
    for (int t = 0; t < 64; ++t) {
        const int c = t * 16 + row;
        long b = (long)c * D + koff;
        bf16x8 bh0 = *(const bf16x8*)(eh + b);
        bf16x8 bh1 = *(const bf16x8*)(eh + b + 32);
        bf16x8 bm0 = *(const bf16x8*)(em + b);
        bf16x8 bm1 = *(const bf16x8*)(em + b + 32);
        float e2c = e2l[c];
#pragma unroll
        for (int s = 0; s < 2; ++s) {
            f32x4 acc = {0.f, 0.f, 0.f, 0.f};
            acc = __builtin_amdgcn_mfma_f32_16x16x32_bf16(ah[s][0], bm0, acc, 0, 0, 0);
            acc = __builtin_amdgcn_mfma_f32_16x16x32_bf16(am[s][0], bh0, acc, 0, 0, 0);
            acc = __builtin_amdgcn_mfma_f32_16x16x32_bf16(ah[s][0], bh0, acc, 0, 0, 0);
            acc = __builtin_amdgcn_mfma_f32_16x16x32_bf16(ah[s][1], bm1, acc, 0, 0, 0);
            acc = __builtin_amdgcn_mfma_f32_16x16x32_bf16(am[s][1], bh1, acc, 0, 0, 0);
            acc = __builtin_amdgcn_mfma_f32_16x16x32_bf16(ah[s][1], bh1, acc, 0, 0, 0);
#pragma unroll
            for (int r = 0; r < 4; ++r) {
                float sd = 0.5f * e2c - acc[r];
                u64 key = ((u64)__float_as_uint(sd + 1024.0f) << 32) | (u32)c;
                int sl = s * 4 + r;
                u64 hi = u64max(t1[sl], key);
                t1[sl] = u64min(t1[sl], key);
                t2[sl] = u64min(t2[sl], hi);
            }
        }
    }

    // merge top-2 across the 16 code-columns (xor 1,2,4,8 stays in-group)
#pragma unroll
    for (int d = 1; d < 16; d <<= 1) {
#pragma unroll
        for (int sl = 0; sl < 8; ++sl) {
            u64 o1 = __shfl_xor(t1[sl], d, 64);
            u64 o2 = __shfl_xor(t2[sl], d, 64);
            u64 nm1 = u64min(t1[sl], o1);
            u64 nm2 = u64min(u64max(t1[sl], o1), u64min(t2[sl], o2));
            t1[sl] = nm1; t2[sl] = nm2;
        }
    }

    if ((l & 15) == 0) {
        const int g = l >> 4;
#pragma unroll
        for (int sl = 0; sl < 8; ++sl) {
            int s = sl >> 2, r = sl & 3;
            int q = qbase + s * 16 + g * 4 + r;
            int bi = (int)(u32)(t1[sl] & 0xFFFFFFFFu);
            idxarr[q] = bi;
            float f1 = __uint_as_float((u32)(t1[sl] >> 32));
            float f2 = __uint_as_float((u32)(t2[sl] >> 32));
            if (f2 - f1 <= MARGIN) {
                u32 p = atomicAdd(cnt, 1u);
                if (p < CAPQ) list[p] = q;
            }
        }
    }
}

// ---------------- K2: exact f32 rescue, one (query,chunk-of-64) per thread --
__global__ __launch_bounds__(256) void vqk2(const float* __restrict__ x,
                                            const float* __restrict__ emb,
                                            const float* __restrict__ e2,
                                            const int* __restrict__ list,
                                            const u32* __restrict__ cnt,
                                            float* __restrict__ pf,
                                            int* __restrict__ pi) {
    u32 n = *cnt; if (n > CAPQ) n = CAPQ;
    int jobs = (int)n * 16;
    for (int j = blockIdx.x * 256 + threadIdx.x; j < jobs; j += gridDim.x * 256) {
        int q = list[j >> 4];
        int ch = j & 15;
        float4 xv[16];
        const float4* xp = (const float4*)(x + (long)q * D);
#pragma unroll
        for (int i = 0; i < 16; ++i) xv[i] = xp[i];
        float best = 3.4e38f; int bidx = 0;
        for (int c0 = 0; c0 < 64; ++c0) {
            int c = ch * 64 + c0;
            const float4* ep = (const float4*)(emb + (long)c * D);
            float a0 = 0.f, a1 = 0.f, a2 = 0.f, a3 = 0.f;
#pragma unroll
            for (int i = 0; i < 16; ++i) {
                float4 e = ep[i];
                a0 = fmaf(e.x, xv[i].x, a0); a1 = fmaf(e.y, xv[i].y, a1);
                a2 = fmaf(e.z, xv[i].z, a2); a3 = fmaf(e.w, xv[i].w, a3);
            }
            float s = 0.5f * e2[c] - ((a0 + a1) + (a2 + a3));
            if (s < best) { best = s; bidx = c; }   // ascending c: first-min
        }
        pf[j] = best; pi[j] = bidx;
    }
}

// ---------------- K2b: merge 16 chunks per rescued query --------------------
__global__ __launch_bounds__(256) void vqk2b(const int* __restrict__ list,
                                             const u32* __restrict__ cnt,
                                             const float* __restrict__ pf,
                                             const int* __restrict__ pi,
                                             int* __restrict__ idxarr) {
    u32 n = *cnt; if (n > CAPQ) n = CAPQ;
    for (int f = threadIdx.x; f < (int)n; f += 256) {
        float b = pf[f * 16]; int bi = pi[f * 16];
#pragma unroll
        for (int k = 1; k < 16; ++k) {
            float s = pf[f * 16 + k]; int c = pi[f * 16 + k];
            if (s < b || (s == b && c < bi)) { b = s; bi = c; }
        }
        idxarr[list[f]] = bi;
    }
}

// ---------------- K3: gather quantized, write idx, loss partials ------------
// 4096 blocks x 256 thr: wave handles 4 queries, 16 lanes each (coalesced).
__global__ __launch_bounds__(256) void vqk3(const float* __restrict__ x,
                                            const float* __restrict__ emb,
                                            const int* __restrict__ idxarr,
                                            float* __restrict__ out,
                                            float* __restrict__ lp) {
    __shared__ float sm[4];
    const int tid = threadIdx.x;
    const int l = tid & 63;
    const int w = tid >> 6;
    const int q = blockIdx.x * 16 + w * 4 + (l >> 4);
    const int d0 = (l & 15) * 4;

    int idx = idxarr[q];
    float4 xv = *(const float4*)(x + (long)q * D + d0);
    float4 ev = *(const float4*)(emb + (long)idx * D + d0);
    *(float4*)(out + (long)q * D + d0) = ev;
    if ((l & 15) == 0) out[IDX_OUT_OFF + q] = (float)idx;

    float dx = ev.x - xv.x, dy = ev.y - xv.y, dz = ev.z - xv.z, dw = ev.w - xv.w;
    float ls = dx * dx + dy * dy + dz * dz + dw * dw;
#pragma unroll
    for (int o = 32; o > 0; o >>= 1) ls += __shfl_down(ls, o, 64);
    if (l == 0) sm[w] = ls;
    __syncthreads();
    if (tid == 0) lp[blockIdx.x] = sm[0] + sm[1] + sm[2] + sm[3];
}

// ---------------- K4: loss tail ---------------------------------------------
__global__ __launch_bounds__(256) void vqk4(const float* __restrict__ lp,
                                            float* __restrict__ out) {
    __shared__ float sm[4];
    const int tid = threadIdx.x;
    float s = 0.f;
#pragma unroll
    for (int i = 0; i < 16; ++i) s += lp[tid + 256 * i];
#pragma unroll
    for (int o = 32; o > 0; o >>= 1) s += __shfl_down(s, o, 64);
    if ((tid & 63) == 0) sm[tid >> 6] = s;
    __syncthreads();
    if (tid == 0) out[LOSS_OFF] = (sm[0] + sm[1] + sm[2] + sm[3]) * (0.25f / (float)NELEM);
}

// ================== R3 fallback (ws too small) ==============================
#define FDO_CHUNK(B, K) \
    aA0 = fmaf(B[0],  xA[4*K+0].x, aA0); aA1 = fmaf(B[1],  xA[4*K+0].y, aA1); \
    aA2 = fmaf(B[2],  xA[4*K+0].z, aA2); aA3 = fmaf(B[3],  xA[4*K+0].w, aA3); \
    aA0 = fmaf(B[4],  xA[4*K+1].x, aA0); aA1 = fmaf(B[5],  xA[4*K+1].y, aA1); \
    aA2 = fmaf(B[6],  xA[4*K+1].z, aA2); aA3 = fmaf(B[7],  xA[4*K+1].w, aA3); \
    aA0 = fmaf(B[8],  xA[4*K+2].x, aA0); aA1 = fmaf(B[9],  xA[4*K+2].y, aA1); \
    aA2 = fmaf(B[10], xA[4*K+2].z, aA2); aA3 = fmaf(B[11], xA[4*K+2].w, aA3); \
    aA0 = fmaf(B[12], xA[4*K+3].x, aA0); aA1 = fmaf(B[13], xA[4*K+3].y, aA1); \
    aA2 = fmaf(B[14], xA[4*K+3].z, aA2); aA3 = fmaf(B[15], xA[4*K+3].w, aA3); \
    aB0 = fmaf(B[0],  xB[4*K+0].x, aB0); aB1 = fmaf(B[1],  xB[4*K+0].y, aB1); \
    aB2 = fmaf(B[2],  xB[4*K+0].z, aB2); aB3 = fmaf(B[3],  xB[4*K+0].w, aB3); \
    aB0 = fmaf(B[4],  xB[4*K+1].x, aB0); aB1 = fmaf(B[5],  xB[4*K+1].y, aB1); \
    aB2 = fmaf(B[6],  xB[4*K+1].z, aB2); aB3 = fmaf(B[7],  xB[4*K+1].w, aB3); \
    aB0 = fmaf(B[8],  xB[4*K+2].x, aB0); aB1 = fmaf(B[9],  xB[4*K+2].y, aB1); \
    aB2 = fmaf(B[10], xB[4*K+2].z, aB2); aB3 = fmaf(B[11], xB[4*K+2].w, aB3); \
    aB0 = fmaf(B[12], xB[4*K+3].x, aB0); aB1 = fmaf(B[13], xB[4*K+3].y, aB1); \
    aB2 = fmaf(B[14], xB[4*K+3].z, aB2); aB3 = fmaf(B[15], xB[4*K+3].w, aB3);

__global__ __launch_bounds__(256) void vq_e2f(const float* __restrict__ emb,
                                              float* __restrict__ e2,
                                              float* __restrict__ out) {
    int k = blockIdx.x * blockDim.x + threadIdx.x;
    if (k == 0) out[LOSS_OFF] = 0.0f;
    if (k < NK) {
        const float4* e4 = (const float4*)(emb + k * D);
        float s = 0.f;
#pragma unroll
        for (int i = 0; i < D / 4; ++i) {
            float4 v = e4[i];
            s += v.x * v.x + v.y * v.y + v.z * v.z + v.w * v.w;
        }
        e2[k] = s;
    }
}

__global__ __launch_bounds__(256, 2) void vq_mainf(const float* __restrict__ x,
                                                   const float* __restrict__ emb,
                                                   const float* __restrict__ e2g,
                                                   float* __restrict__ out) {
    __shared__ float e2l[NK];
    __shared__ float sm_s[512];
    __shared__ int   sm_c[512];
    const int tid = threadIdx.x;
    const int l = tid & 63;
    const int w = tid >> 6;
    const int qbase = blockIdx.x * 128;
    ((float4*)e2l)[tid] = ((const float4*)e2g)[tid];
    float4 xA[16], xB[16];
    const float4* xpA = (const float4*)(x + (long)(qbase + l) * D);
    const float4* xpB = (const float4*)(x + (long)(qbase + 64 + l) * D);
#pragma unroll
    for (int i = 0; i < 16; ++i) { xA[i] = xpA[i]; xB[i] = xpB[i]; }
    __syncthreads();
    const int code0 = __builtin_amdgcn_readfirstlane(w << 8);
    const float* ep0 = emb + (long)code0 * D;
    float bestA = 3.4e38f, bestB = 3.4e38f;
    int idxA = 0, idxB = 0;
#pragma unroll 1
    for (int g = 0; g < 256; ++g) {
        const float* ep = ep0 + g * D;
        f32x16 b0, b1, b2, b3;
        asm volatile(
            "s_load_dwordx16 %0, %4, 0x0\n\t"
            "s_load_dwordx16 %1, %4, 0x40\n\t"
            "s_load_dwordx16 %2, %4, 0x80\n\t"
            "s_load_dwordx16 %3, %4, 0xC0\n\t"
            "s_waitcnt lgkmcnt(0)"
            : "=s"(b0), "=s"(b1), "=s"(b2), "=s"(b3) : "s"(ep));
        float aA0 = 0.f, aA1 = 0.f, aA2 = 0.f, aA3 = 0.f;
        float aB0 = 0.f, aB1 = 0.f, aB2 = 0.f, aB3 = 0.f;
        FDO_CHUNK(b0, 0) FDO_CHUNK(b1, 1) FDO_CHUNK(b2, 2) FDO_CHUNK(b3, 3)
        float dotA = (aA0 + aA1) + (aA2 + aA3);
        float dotB = (aB0 + aB1) + (aB2 + aB3);
        float e2c = e2l[code0 + g];
        float sA = 0.5f * e2c - dotA;
        float sB = 0.5f * e2c - dotB;
        int code = code0 + g;
        bool lt;
        lt = sA < bestA; bestA = lt ? sA : bestA; idxA = lt ? code : idxA;
        lt = sB < bestB; bestB = lt ? sB : bestB; idxB = lt ? code : idxB;
    }
    sm_s[w * 128 + l] = bestA;      sm_c[w * 128 + l] = idxA;
    sm_s[w * 128 + 64 + l] = bestB; sm_c[w * 128 + 64 + l] = idxB;
    __syncthreads();
    if (tid < 128) {
        float bs = sm_s[tid]; int bc = sm_c[tid];
#pragma unroll
        for (int wv = 1; wv < 4; ++wv) {
            float s = sm_s[wv * 128 + tid]; int c = sm_c[wv * 128 + tid];
            if (s < bs) { bs = s; bc = c; }
        }
        const int q = qbase + tid;
        out[IDX_OUT_OFF + q] = (float)bc;
        const float4* eb = (const float4*)(emb + (long)bc * D);
        const float4* xq = (const float4*)(x + (long)q * D);
        float4* oq = (float4*)(out + (long)q * D);
        float lsum = 0.f;
#pragma unroll
        for (int i = 0; i < 16; ++i) {
            float4 e = eb[i]; float4 xx = xq[i];
            oq[i] = e;
            float dx = e.x - xx.x, dy = e.y - xx.y, dz = e.z - xx.z, dw = e.w - xx.w;
            lsum += dx * dx + dy * dy + dz * dz + dw * dw;
        }
#pragma unroll
        for (int o = 32; o > 0; o >>= 1) lsum += __shfl_down(lsum, o, 64);
        if ((tid & 63) == 0) atomicAdd(&out[LOSS_OFF], lsum * (0.25f / (float)NELEM));
    }
}

extern "C" void kernel_launch(void* const* d_in, const int* in_sizes, int n_in,
                              void* d_out, int out_size, void* d_ws, size_t ws_size,
                              hipStream_t stream) {
    const float* x   = (const float*)d_in[0];
    const float* emb = (const float*)d_in[1];
    float* out = (float*)d_out;
    char* ws = (char*)d_ws;

    if (ws_size < (size_t)WS_NEED) {           // fallback: proven R3 path
        float* e2 = (float*)ws;
        vq_e2f<<<4, 256, 0, stream>>>(emb, e2, out);
        vq_mainf<<<QTOTAL / 128, 256, 0, stream>>>(x, emb, e2, out);
        return;
    }

    float* e2   = (float*)(ws + WS_E2);
    ushort_t* eh = (ushort_t*)(ws + WS_EH);
    ushort_t* em = (ushort_t*)(ws + WS_EM);
    int* idxa   = (int*)(ws + WS_IDX);
    u32* cnt    = (u32*)(ws + WS_CNT);
    int* list   = (int*)(ws + WS_LIST);
    float* pf   = (float*)(ws + WS_PF);
    int* pi     = (int*)(ws + WS_PI);
    float* lp   = (float*)(ws + WS_LP);
    // bf16 splits of x live in out's quantized region (overwritten by vqk3)
    ushort_t* xh = (ushort_t*)out;
    ushort_t* xm = xh + NELEM;

    vqk0<<<2048, 256, 0, stream>>>(x, emb, (u32*)xh, (u32*)xm, (u32*)eh, (u32*)em, e2, cnt);
    vqk1<<<512, 256, 0, stream>>>(xh, xm, eh, em, e2, idxa, list, cnt);
    vqk2<<<64, 256, 0, stream>>>(x, emb, e2, list, cnt, pf, pi);
    vqk2b<<<1, 256, 0, stream>>>(list, cnt, pf, pi, idxa);
    vqk3<<<4096, 256, 0, stream>>>(x, emb, idxa, out, lp);
    vqk4<<<1, 256, 0, stream>>>(lp, out);
}

// Round 8
// 158.743 us; speedup vs baseline: 1.7976x; 1.7688x over previous
//
#include <hip/hip_runtime.h>

#define D 64
#define NK 1024
#define QTOTAL 65536
#define NELEM (QTOTAL * D)
#define LOSS_OFF 4194304
#define IDX_OUT_OFF 4194305
#define CAPQ 16384
#define MARGIN 2.0e-3f

typedef float f32x16 __attribute__((ext_vector_type(16)));
typedef short bf16x8 __attribute__((ext_vector_type(8)));
typedef float f32x4 __attribute__((ext_vector_type(4)));
typedef unsigned long long u64;
typedef unsigned int u32;
typedef unsigned short ushort_t;

// ---- ws layout (bytes) ----
#define WS_E2   0          // 1024 f32
#define WS_EH   4096       // 65536 bf16
#define WS_EM   135168     // 65536 bf16
#define WS_IDX  266240     // 65536 i32
#define WS_CNT  528384     // u32 (+pad)
#define WS_LIST 528640     // 16384 i32
#define WS_LP   594176     // 4096 f32
#define WS_NEED 610560

__device__ __forceinline__ ushort_t f2bf(float f) {
    u32 u = __float_as_uint(f);
    return (ushort_t)((u + 0x7FFFu + ((u >> 16) & 1u)) >> 16);
}
__device__ __forceinline__ float bf2f(ushort_t h) {
    return __uint_as_float(((u32)h) << 16);
}

// split 8 f32 (two float4) -> bf16 hi frag + bf16 mid frag
__device__ __forceinline__ void split8(float4 a, float4 b, bf16x8* h, bf16x8* m) {
    float v[8] = {a.x, a.y, a.z, a.w, b.x, b.y, b.z, b.w};
#pragma unroll
    for (int i = 0; i < 8; ++i) {
        ushort_t hs = f2bf(v[i]);
        ushort_t ms = f2bf(v[i] - bf2f(hs));
        (*h)[i] = (short)hs;
        (*m)[i] = (short)ms;
    }
}

// ---------------- K0: split emb into bf16 hi/mid; e2; zero counter ----------
__global__ __launch_bounds__(256) void vqk0(const float* __restrict__ emb,
                                            u32* __restrict__ eh32, u32* __restrict__ em32,
                                            float* __restrict__ e2, u32* __restrict__ cnt) {
    int gid = blockIdx.x * 256 + threadIdx.x;   // 128 blocks -> 32768 threads
    float2 v = ((const float2*)emb)[gid];
    ushort_t h0 = f2bf(v.x), h1 = f2bf(v.y);
    ushort_t m0 = f2bf(v.x - bf2f(h0)), m1 = f2bf(v.y - bf2f(h1));
    eh32[gid] = (u32)h0 | ((u32)h1 << 16);
    em32[gid] = (u32)m0 | ((u32)m1 << 16);
    if (gid < NK) {                             // exact f32 |e|^2
        const float4* e4 = (const float4*)(emb + (long)gid * D);
        float s = 0.f;
#pragma unroll
        for (int i = 0; i < D / 4; ++i) {
            float4 w = e4[i];
            s += w.x * w.x + w.y * w.y + w.z * w.z + w.w * w.w;
        }
        e2[gid] = s;
    }
    if (gid == 0) *cnt = 0;
}

// ---------------- K1: bf16x2 MFMA coarse top-2 + margin flag ----------------
// 512 blocks x 256 thr (4 waves). Wave owns 32 queries (2 sub-tiles of 16),
// scans all 64 code-tiles. dot = hh+hm+mh (error ~1e-4 << MARGIN). x is split
// to bf16 hi/mid IN-REGISTER (no global round trip). Fragment layout
// (R7-validated): A[m=lane&15][k=(lane>>4)*8+j]; C/D col=lane&15 (code),
// row=(lane>>4)*4+reg (query).
__global__ __launch_bounds__(256) void vqk1(const float* __restrict__ x,
                                            const ushort_t* __restrict__ eh,
                                            const ushort_t* __restrict__ em,
                                            const float* __restrict__ e2g,
                                            int* __restrict__ idxarr,
                                            int* __restrict__ list,
                                            u32* __restrict__ cnt) {
    __shared__ float e2l[NK];
    const int tid = threadIdx.x;
    const int l = tid & 63;
    const int w = tid >> 6;
    for (int i = tid; i < NK; i += 256) e2l[i] = e2g[i];
    __syncthreads();

    const int row = l & 15;
    const int koff = (l >> 4) * 8;
    const int qbase = blockIdx.x * 128 + w * 32;

    bf16x8 ah[2][2], am[2][2];
#pragma unroll
    for (int s = 0; s < 2; ++s) {
        const float* xr = x + (long)(qbase + s * 16 + row) * D + koff;
        float4 p0 = ((const float4*)xr)[0];
        float4 p1 = ((const float4*)xr)[1];
        float4 p2 = ((const float4*)(xr + 32))[0];
        float4 p3 = ((const float4*)(xr + 32))[1];
        split8(p0, p1, &ah[s][0], &am[s][0]);
        split8(p2, p3, &ah[s][1], &am[s][1]);
    }

    float s1v[8], s2v[8];
    int i1v[8];
#pragma unroll
    for (int i = 0; i < 8; ++i) { s1v[i] = 3.4e38f; s2v[i] = 3.4e38f; i1v[i] = 0; }

#pragma unroll 1
    for (int t = 0; t < 64; ++t) {
        const int c = t * 16 + row;
        long b = (long)c * D + koff;
        bf16x8 bh0 = *(const bf16x8*)(eh + b);
        bf16x8 bh1 = *(const bf16x8*)(eh + b + 32);
        bf16x8 bm0 = *(const bf16x8*)(em + b);
        bf16x8 bm1 = *(const bf16x8*)(em + b + 32);
        float h = 0.5f * e2l[c];
#pragma unroll
        for (int s = 0; s < 2; ++s) {
            f32x4 acc = {0.f, 0.f, 0.f, 0.f};
            acc = __builtin_amdgcn_mfma_f32_16x16x32_bf16(ah[s][0], bm0, acc, 0, 0, 0);
            acc = __builtin_amdgcn_mfma_f32_16x16x32_bf16(am[s][0], bh0, acc, 0, 0, 0);
            acc = __builtin_amdgcn_mfma_f32_16x16x32_bf16(ah[s][0], bh0, acc, 0, 0, 0);
            acc = __builtin_amdgcn_mfma_f32_16x16x32_bf16(ah[s][1], bm1, acc, 0, 0, 0);
            acc = __builtin_amdgcn_mfma_f32_16x16x32_bf16(am[s][1], bh1, acc, 0, 0, 0);
            acc = __builtin_amdgcn_mfma_f32_16x16x32_bf16(ah[s][1], bh1, acc, 0, 0, 0);
#pragma unroll
            for (int r = 0; r < 4; ++r) {
                int sl = s * 4 + r;
                float sd = h - acc[r];
                bool lt = sd < s1v[sl];
                float cand = lt ? s1v[sl] : sd;      // displaced-or-new second
                s2v[sl] = cand < s2v[sl] ? cand : s2v[sl];
                s1v[sl] = lt ? sd : s1v[sl];
                i1v[sl] = lt ? c : i1v[sl];
            }
        }
    }

    // merge top-2 across the 16 code-columns (xor 1,2,4,8 stays in-group);
    // lowest-index wins on exact s1 tie.
#pragma unroll
    for (int d = 1; d < 16; d <<= 1) {
#pragma unroll
        for (int sl = 0; sl < 8; ++sl) {
            float os1 = __shfl_xor(s1v[sl], d, 64);
            float os2 = __shfl_xor(s2v[sl], d, 64);
            int   oi1 = __shfl_xor(i1v[sl], d, 64);
            float hi = s1v[sl] > os1 ? s1v[sl] : os1;
            float lo2 = s2v[sl] < os2 ? s2v[sl] : os2;
            int ni = (os1 < s1v[sl]) ? oi1
                   : ((os1 == s1v[sl] && oi1 < i1v[sl]) ? oi1 : i1v[sl]);
            s1v[sl] = s1v[sl] < os1 ? s1v[sl] : os1;
            s2v[sl] = hi < lo2 ? hi : lo2;
            i1v[sl] = ni;
        }
    }

    if ((l & 15) == 0) {
        const int g = l >> 4;
#pragma unroll
        for (int sl = 0; sl < 8; ++sl) {
            int s = sl >> 2, r = sl & 3;
            int q = qbase + s * 16 + g * 4 + r;
            idxarr[q] = i1v[sl];
            if (s2v[sl] - s1v[sl] <= MARGIN) {
                u32 p = atomicAdd(cnt, 1u);
                if (p < CAPQ) list[p] = q;
            }
        }
    }
}

// ---------------- K2: exact f32 rescue, ONE WAVE per rescued query ----------
// 64 lanes x 16 codes each, loads independent & L2-hot -> latency hidden.
__global__ __launch_bounds__(64) void vqk2(const float* __restrict__ x,
                                           const float* __restrict__ emb,
                                           const float* __restrict__ e2,
                                           const int* __restrict__ list,
                                           const u32* __restrict__ cnt,
                                           int* __restrict__ idxarr) {
    u32 n = *cnt; if (n > CAPQ) n = CAPQ;
    const int l = threadIdx.x;
    for (u32 f = blockIdx.x; f < n; f += gridDim.x) {
        int q = list[f];
        float4 xv[16];
        const float4* xp = (const float4*)(x + (long)q * D);
#pragma unroll
        for (int i = 0; i < 16; ++i) xv[i] = xp[i];
        float best = 3.4e38f; int bidx = 0;
#pragma unroll 1
        for (int i = 0; i < 16; ++i) {
            int c = l * 16 + i;                 // lane covers [l*16, l*16+16)
            const float4* ep = (const float4*)(emb + (long)c * D);
            float a0 = 0.f, a1 = 0.f, a2 = 0.f, a3 = 0.f;
#pragma unroll
            for (int k = 0; k < 16; ++k) {
                float4 e = ep[k];
                a0 = fmaf(e.x, xv[k].x, a0); a1 = fmaf(e.y, xv[k].y, a1);
                a2 = fmaf(e.z, xv[k].z, a2); a3 = fmaf(e.w, xv[k].w, a3);
            }
            float s = 0.5f * e2[c] - ((a0 + a1) + (a2 + a3));
            if (s < best) { best = s; bidx = c; }   // ascending c: first-min
        }
        // cross-lane min with lowest-index tie-break (exact semantics)
#pragma unroll
        for (int off = 32; off > 0; off >>= 1) {
            float ob = __shfl_down(best, off, 64);
            int   oi = __shfl_down(bidx, off, 64);
            if (ob < best || (ob == best && oi < bidx)) { best = ob; bidx = oi; }
        }
        if (l == 0) idxarr[q] = bidx;
    }
}

// ---------------- K3: gather quantized, write idx, loss partials ------------
__global__ __launch_bounds__(256) void vqk3(const float* __restrict__ x,
                                            const float* __restrict__ emb,
                                            const int* __restrict__ idxarr,
                                            float* __restrict__ out,
                                            float* __restrict__ lp) {
    __shared__ float sm[4];
    const int tid = threadIdx.x;
    const int l = tid & 63;
    const int w = tid >> 6;
    const int q = blockIdx.x * 16 + w * 4 + (l >> 4);
    const int d0 = (l & 15) * 4;

    int idx = idxarr[q];
    float4 xv = *(const float4*)(x + (long)q * D + d0);
    float4 ev = *(const float4*)(emb + (long)idx * D + d0);
    *(float4*)(out + (long)q * D + d0) = ev;
    if ((l & 15) == 0) out[IDX_OUT_OFF + q] = (float)idx;

    float dx = ev.x - xv.x, dy = ev.y - xv.y, dz = ev.z - xv.z, dw = ev.w - xv.w;
    float ls = dx * dx + dy * dy + dz * dz + dw * dw;
#pragma unroll
    for (int o = 32; o > 0; o >>= 1) ls += __shfl_down(ls, o, 64);
    if (l == 0) sm[w] = ls;
    __syncthreads();
    if (tid == 0) lp[blockIdx.x] = sm[0] + sm[1] + sm[2] + sm[3];
}

// ---------------- K4: loss tail ---------------------------------------------
__global__ __launch_bounds__(256) void vqk4(const float* __restrict__ lp,
                                            float* __restrict__ out) {
    __shared__ float sm[4];
    const int tid = threadIdx.x;
    float s = 0.f;
#pragma unroll
    for (int i = 0; i < 16; ++i) s += lp[tid + 256 * i];
#pragma unroll
    for (int o = 32; o > 0; o >>= 1) s += __shfl_down(s, o, 64);
    if ((tid & 63) == 0) sm[tid >> 6] = s;
    __syncthreads();
    if (tid == 0) out[LOSS_OFF] = (sm[0] + sm[1] + sm[2] + sm[3]) * (0.25f / (float)NELEM);
}

// ================== R3 fallback (ws too small) ==============================
#define FDO_CHUNK(B, K) \
    aA0 = fmaf(B[0],  xA[4*K+0].x, aA0); aA1 = fmaf(B[1],  xA[4*K+0].y, aA1); \
    aA2 = fmaf(B[2],  xA[4*K+0].z, aA2); aA3 = fmaf(B[3],  xA[4*K+0].w, aA3); \
    aA0 = fmaf(B[4],  xA[4*K+1].x, aA0); aA1 = fmaf(B[5],  xA[4*K+1].y, aA1); \
    aA2 = fmaf(B[6],  xA[4*K+1].z, aA2); aA3 = fmaf(B[7],  xA[4*K+1].w, aA3); \
    aA0 = fmaf(B[8],  xA[4*K+2].x, aA0); aA1 = fmaf(B[9],  xA[4*K+2].y, aA1); \
    aA2 = fmaf(B[10], xA[4*K+2].z, aA2); aA3 = fmaf(B[11], xA[4*K+2].w, aA3); \
    aA0 = fmaf(B[12], xA[4*K+3].x, aA0); aA1 = fmaf(B[13], xA[4*K+3].y, aA1); \
    aA2 = fmaf(B[14], xA[4*K+3].z, aA2); aA3 = fmaf(B[15], xA[4*K+3].w, aA3); \
    aB0 = fmaf(B[0],  xB[4*K+0].x, aB0); aB1 = fmaf(B[1],  xB[4*K+0].y, aB1); \
    aB2 = fmaf(B[2],  xB[4*K+0].z, aB2); aB3 = fmaf(B[3],  xB[4*K+0].w, aB3); \
    aB0 = fmaf(B[4],  xB[4*K+1].x, aB0); aB1 = fmaf(B[5],  xB[4*K+1].y, aB1); \
    aB2 = fmaf(B[6],  xB[4*K+1].z, aB2); aB3 = fmaf(B[7],  xB[4*K+1].w, aB3); \
    aB0 = fmaf(B[8],  xB[4*K+2].x, aB0); aB1 = fmaf(B[9],  xB[4*K+2].y, aB1); \
    aB2 = fmaf(B[10], xB[4*K+2].z, aB2); aB3 = fmaf(B[11], xB[4*K+2].w, aB3); \
    aB0 = fmaf(B[12], xB[4*K+3].x, aB0); aB1 = fmaf(B[13], xB[4*K+3].y, aB1); \
    aB2 = fmaf(B[14], xB[4*K+3].z, aB2); aB3 = fmaf(B[15], xB[4*K+3].w, aB3);

__global__ __launch_bounds__(256) void vq_e2f(const float* __restrict__ emb,
                                              float* __restrict__ e2,
                                              float* __restrict__ out) {
    int k = blockIdx.x * blockDim.x + threadIdx.x;
    if (k == 0) out[LOSS_OFF] = 0.0f;
    if (k < NK) {
        const float4* e4 = (const float4*)(emb + k * D);
        float s = 0.f;
#pragma unroll
        for (int i = 0; i < D / 4; ++i) {
            float4 v = e4[i];
            s += v.x * v.x + v.y * v.y + v.z * v.z + v.w * v.w;
        }
        e2[k] = s;
    }
}

__global__ __launch_bounds__(256, 2) void vq_mainf(const float* __restrict__ x,
                                                   const float* __restrict__ emb,
                                                   const float* __restrict__ e2g,
                                                   float* __restrict__ out) {
    __shared__ float e2l[NK];
    __shared__ float sm_s[512];
    __shared__ int   sm_c[512];
    const int tid = threadIdx.x;
    const int l = tid & 63;
    const int w = tid >> 6;
    const int qbase = blockIdx.x * 128;
    ((float4*)e2l)[tid] = ((const float4*)e2g)[tid];
    float4 xA[16], xB[16];
    const float4* xpA = (const float4*)(x + (long)(qbase + l) * D);
    const float4* xpB = (const float4*)(x + (long)(qbase + 64 + l) * D);
#pragma unroll
    for (int i = 0; i < 16; ++i) { xA[i] = xpA[i]; xB[i] = xpB[i]; }
    __syncthreads();
    const int code0 = __builtin_amdgcn_readfirstlane(w << 8);
    const float* ep0 = emb + (long)code0 * D;
    float bestA = 3.4e38f, bestB = 3.4e38f;
    int idxA = 0, idxB = 0;
#pragma unroll 1
    for (int g = 0; g < 256; ++g) {
        const float* ep = ep0 + g * D;
        f32x16 b0, b1, b2, b3;
        asm volatile(
            "s_load_dwordx16 %0, %4, 0x0\n\t"
            "s_load_dwordx16 %1, %4, 0x40\n\t"
            "s_load_dwordx16 %2, %4, 0x80\n\t"
            "s_load_dwordx16 %3, %4, 0xC0\n\t"
            "s_waitcnt lgkmcnt(0)"
            : "=s"(b0), "=s"(b1), "=s"(b2), "=s"(b3) : "s"(ep));
        float aA0 = 0.f, aA1 = 0.f, aA2 = 0.f, aA3 = 0.f;
        float aB0 = 0.f, aB1 = 0.f, aB2 = 0.f, aB3 = 0.f;
        FDO_CHUNK(b0, 0) FDO_CHUNK(b1, 1) FDO_CHUNK(b2, 2) FDO_CHUNK(b3, 3)
        float dotA = (aA0 + aA1) + (aA2 + aA3);
        float dotB = (aB0 + aB1) + (aB2 + aB3);
        float e2c = e2l[code0 + g];
        float sA = 0.5f * e2c - dotA;
        float sB = 0.5f * e2c - dotB;
        int code = code0 + g;
        bool lt;
        lt = sA < bestA; bestA = lt ? sA : bestA; idxA = lt ? code : idxA;
        lt = sB < bestB; bestB = lt ? sB : bestB; idxB = lt ? code : idxB;
    }
    sm_s[w * 128 + l] = bestA;      sm_c[w * 128 + l] = idxA;
    sm_s[w * 128 + 64 + l] = bestB; sm_c[w * 128 + 64 + l] = idxB;
    __syncthreads();
    if (tid < 128) {
        float bs = sm_s[tid]; int bc = sm_c[tid];
#pragma unroll
        for (int wv = 1; wv < 4; ++wv) {
            float s = sm_s[wv * 128 + tid]; int c = sm_c[wv * 128 + tid];
            if (s < bs) { bs = s; bc = c; }
        }
        const int q = qbase + tid;
        out[IDX_OUT_OFF + q] = (float)bc;
        const float4* eb = (const float4*)(emb + (long)bc * D);
        const float4* xq = (const float4*)(x + (long)q * D);
        float4* oq = (float4*)(out + (long)q * D);
        float lsum = 0.f;
#pragma unroll
        for (int i = 0; i < 16; ++i) {
            float4 e = eb[i]; float4 xx = xq[i];
            oq[i] = e;
            float dx = e.x - xx.x, dy = e.y - xx.y, dz = e.z - xx.z, dw = e.w - xx.w;
            lsum += dx * dx + dy * dy + dz * dz + dw * dw;
        }
#pragma unroll
        for (int o = 32; o > 0; o >>= 1) lsum += __shfl_down(lsum, o, 64);
        if ((tid & 63) == 0) atomicAdd(&out[LOSS_OFF], lsum * (0.25f / (float)NELEM));
    }
}

extern "C" void kernel_launch(void* const* d_in, const int* in_sizes, int n_in,
                              void* d_out, int out_size, void* d_ws, size_t ws_size,
                              hipStream_t stream) {
    const float* x   = (const float*)d_in[0];
    const float* emb = (const float*)d_in[1];
    float* out = (float*)d_out;
    char* ws = (char*)d_ws;

    if (ws_size < (size_t)WS_NEED) {           // fallback: proven R3 path
        float* e2 = (float*)ws;
        vq_e2f<<<4, 256, 0, stream>>>(emb, e2, out);
        vq_mainf<<<QTOTAL / 128, 256, 0, stream>>>(x, emb, e2, out);
        return;
    }

    float* e2    = (float*)(ws + WS_E2);
    ushort_t* eh = (ushort_t*)(ws + WS_EH);
    ushort_t* em = (ushort_t*)(ws + WS_EM);
    int* idxa    = (int*)(ws + WS_IDX);
    u32* cnt     = (u32*)(ws + WS_CNT);
    int* list    = (int*)(ws + WS_LIST);
    float* lp    = (float*)(ws + WS_LP);

    vqk0<<<128, 256, 0, stream>>>(emb, (u32*)eh, (u32*)em, e2, cnt);
    vqk1<<<512, 256, 0, stream>>>(x, eh, em, e2, idxa, list, cnt);
    vqk2<<<2048, 64, 0, stream>>>(x, emb, e2, list, cnt, idxa);
    vqk3<<<4096, 256, 0, stream>>>(x, emb, idxa, out, lp);
    vqk4<<<1, 256, 0, stream>>>(lp, out);
}